// Round 1
// baseline (5045.700 us; speedup 1.0000x reference)
//
#include <hip/hip_runtime.h>

// Model: 2-layer LSTM encoder (S=128) + attention decoder (T=64), B=64, H=1024, V=32000.
// Strategy: precompute all x@Wx as big MFMA GEMMs; sequential chain only does h@Wh (319 steps);
// decoder recurrence runs before the (fully batched) attention+projection+loss.

#define Bv 64
#define Sv 128
#define Tv 64
#define Hv 1024
#define H4v 4096
#define Vv 32000

using bf16x8 = __attribute__((ext_vector_type(8))) short;
using f32x4  = __attribute__((ext_vector_type(4))) float;

typedef __attribute__((address_space(1))) const void gvoid_t;
typedef __attribute__((address_space(3))) void lvoid_t;

__device__ __forceinline__ void gload16(const void* g, void* l) {
  __builtin_amdgcn_global_load_lds((gvoid_t*)g, (lvoid_t*)l, 16, 0, 0);
}

__device__ __forceinline__ float bf2f(unsigned short u) {
  unsigned int v = ((unsigned int)u) << 16;
  return __uint_as_float(v);
}
__device__ __forceinline__ unsigned short f2bf(float f) {
  unsigned int u = __float_as_uint(f);
  return (unsigned short)((u + 0x7FFFu + ((u >> 16) & 1u)) >> 16);
}
__device__ __forceinline__ float sigm(float x) { return 1.f / (1.f + __expf(-x)); }

// ---------------- transpose + fp32->bf16 convert: out[C][R] = bf16(in[R][C]) ----------------
__global__ __launch_bounds__(256) void transpose_bf16(const float* __restrict__ in,
                                                      unsigned short* __restrict__ out,
                                                      int R, int C) {
  __shared__ float tile[32][33];
  int tx = threadIdx.x, ty = threadIdx.y;
  int c0 = blockIdx.x * 32, r0 = blockIdx.y * 32;
#pragma unroll
  for (int i = 0; i < 32; i += 8)
    tile[ty + i][tx] = in[(size_t)(r0 + ty + i) * C + c0 + tx];
  __syncthreads();
#pragma unroll
  for (int i = 0; i < 32; i += 8)
    out[(size_t)(c0 + ty + i) * R + r0 + tx] = f2bf(tile[tx][ty + i]);
}

// ---------------- embedding gather (fp32 table -> bf16 rows) ----------------
__global__ __launch_bounds__(256) void gather_emb(const int* __restrict__ toks,
                                                  const float* __restrict__ emb,
                                                  unsigned short* __restrict__ dst) {
  int r = blockIdx.x, tid = threadIdx.x;
  int tok = toks[r];
  int j = tid * 4;
  float4 v = *(const float4*)&emb[(size_t)tok * Hv + j];
  ushort4 o;
  o.x = f2bf(v.x); o.y = f2bf(v.y); o.z = f2bf(v.z); o.w = f2bf(v.w);
  *(ushort4*)&dst[(size_t)r * Hv + j] = o;
}

// ---------------- init: zero-h, cell states, decoder h0/m0 broadcast ----------------
__global__ __launch_bounds__(256) void init_k(unsigned short* __restrict__ zh,
                                              float* __restrict__ c1, float* __restrict__ c2,
                                              float* __restrict__ md,
                                              unsigned short* __restrict__ Hdec,
                                              const float* __restrict__ h0,
                                              const float* __restrict__ m0) {
  int idx = blockIdx.x * 256 + threadIdx.x;  // 65536 = 64*1024
  int j = idx & (Hv - 1);
  int b = idx >> 10;
  zh[idx] = 0;
  c1[idx] = 0.f;
  c2[idx] = 0.f;
  md[idx] = m0[j];
  Hdec[(size_t)(b * Tv) * Hv + j] = f2bf(h0[j]);
}

// ---------------- generic 128x128 MFMA GEMM, B pre-transposed [N][K] bf16 ----------------
// EPI: 1 = bf16 out (+bias), 2 = tanh -> bf16 (+bias), 3 = fused logits (exp-sum partials + tgt gather)
template <int EPI>
__global__ __launch_bounds__(256) void gemm128(const unsigned short* __restrict__ A,
                                               const unsigned short* __restrict__ Bt,
                                               const float* __restrict__ bias,
                                               unsigned short* __restrict__ Cbf,
                                               int M, int N, int K,
                                               float* __restrict__ partial,
                                               float* __restrict__ tlog,
                                               const int* __restrict__ tgt) {
  __shared__ unsigned short As[128 * 64];
  __shared__ unsigned short Bs[128 * 64];
  int tid = threadIdx.x, lane = tid & 63, w = tid >> 6;
  int wr = w >> 1, wc = w & 1;
  int m0 = blockIdx.y * 128, n0 = blockIdx.x * 128;
  f32x4 acc[4][4] = {};
  for (int k0 = 0; k0 < K; k0 += 64) {
    __syncthreads();
#pragma unroll
    for (int q = 0; q < 4; ++q) {
      int idx = q * 256 + tid;
      int row = idx >> 3, phys = idx & 7, lg = phys ^ (row & 7);
      gload16(A + (size_t)(m0 + row) * K + k0 + lg * 8, &As[idx * 8]);
    }
#pragma unroll
    for (int q = 0; q < 4; ++q) {
      int idx = q * 256 + tid;
      int row = idx >> 3, phys = idx & 7, lg = phys ^ (row & 7);
      gload16(Bt + (size_t)(n0 + row) * K + k0 + lg * 8, &Bs[idx * 8]);
    }
    __syncthreads();
#pragma unroll
    for (int kk = 0; kk < 64; kk += 32) {
      int lgb = (kk >> 3) + (lane >> 4);
      bf16x8 af[4], bfr[4];
#pragma unroll
      for (int m = 0; m < 4; ++m) {
        int row = wr * 64 + m * 16 + (lane & 15);
        af[m] = *(const bf16x8*)&As[(row * 8 + (lgb ^ (row & 7))) * 8];
      }
#pragma unroll
      for (int n = 0; n < 4; ++n) {
        int row = wc * 64 + n * 16 + (lane & 15);
        bfr[n] = *(const bf16x8*)&Bs[(row * 8 + (lgb ^ (row & 7))) * 8];
      }
#pragma unroll
      for (int m = 0; m < 4; ++m)
#pragma unroll
        for (int n = 0; n < 4; ++n)
          acc[m][n] = __builtin_amdgcn_mfma_f32_16x16x32_bf16(af[m], bfr[n], acc[m][n], 0, 0, 0);
    }
  }
  if (EPI != 3) {
#pragma unroll
    for (int m = 0; m < 4; ++m)
#pragma unroll
      for (int n = 0; n < 4; ++n) {
        int col = n0 + wc * 64 + n * 16 + (lane & 15);
        float bv = bias[col];
#pragma unroll
        for (int j = 0; j < 4; ++j) {
          int row = m0 + wr * 64 + m * 16 + (lane >> 4) * 4 + j;
          float v = acc[m][n][j] + bv;
          if (EPI == 2) v = tanhf(v);
          Cbf[(size_t)row * N + col] = f2bf(v);
        }
      }
  } else {
    int chunk = (n0 + wc * 64) >> 6;  // 64-col chunk owned by this wave
#pragma unroll
    for (int m = 0; m < 4; ++m)
#pragma unroll
      for (int j = 0; j < 4; ++j) {
        int row = m0 + wr * 64 + m * 16 + (lane >> 4) * 4 + j;
        int tv = tgt[row];
        float se = 0.f;
#pragma unroll
        for (int n = 0; n < 4; ++n) {
          int col = n0 + wc * 64 + n * 16 + (lane & 15);
          float v = acc[m][n][j] + bias[col];
          se += __expf(v);  // logits are O(1): no max-subtraction needed
          if (col == tv) tlog[row] = v;
        }
        se += __shfl_xor(se, 1);
        se += __shfl_xor(se, 2);
        se += __shfl_xor(se, 4);
        se += __shfl_xor(se, 8);
        if ((lane & 15) == 0) partial[(size_t)chunk * M + row] = se;
      }
  }
}

// ---------------- fused per-step LSTM: g = Xpre + h@WhT, cell update ----------------
// Block: 4 waves; wave w computes gate w over [64 rows x 16 cols]; grid = 64 (j-tiles).
__global__ __launch_bounds__(256) void lstm_step(const unsigned short* __restrict__ Hprev, int hstride,
                                                 const unsigned short* __restrict__ Xpre, int xstride,
                                                 const unsigned short* __restrict__ WhT,
                                                 float* __restrict__ cbuf,
                                                 unsigned short* __restrict__ Hout, int ostride) {
  __shared__ unsigned short As[64 * 64];       // h tile [64 rows][64 k]
  __shared__ unsigned short Bs[4 * 16 * 64];   // WhT tiles per gate [16 rows][64 k]
  __shared__ float gl[4][64][16];
  int tid = threadIdx.x, lane = tid & 63, w = tid >> 6;
  int j0 = blockIdx.x * 16;
  f32x4 acc[4] = {};
  for (int k0 = 0; k0 < Hv; k0 += 64) {
    __syncthreads();
#pragma unroll
    for (int q = 0; q < 2; ++q) {
      int idx = q * 256 + tid;
      int row = idx >> 3, phys = idx & 7, lg = phys ^ (row & 7);
      gload16(Hprev + (size_t)row * hstride + k0 + lg * 8, &As[idx * 8]);
    }
#pragma unroll
    for (int q = 0; q < 2; ++q) {
      int idx = q * 256 + tid;
      int gate = idx >> 7, rr = (idx >> 3) & 15, phys = idx & 7, lg = phys ^ (rr & 7);
      gload16(WhT + ((size_t)(gate * Hv + j0 + rr)) * Hv + k0 + lg * 8, &Bs[idx * 8]);
    }
    __syncthreads();
#pragma unroll
    for (int kk = 0; kk < 64; kk += 32) {
      int lgb = (kk >> 3) + (lane >> 4);
      int rr = lane & 15;
      bf16x8 bfr = *(const bf16x8*)&Bs[((w * 16 + rr) * 8 + (lgb ^ (rr & 7))) * 8];
#pragma unroll
      for (int m = 0; m < 4; ++m) {
        int row = m * 16 + (lane & 15);
        bf16x8 af = *(const bf16x8*)&As[(row * 8 + (lgb ^ (row & 7))) * 8];
        acc[m] = __builtin_amdgcn_mfma_f32_16x16x32_bf16(af, bfr, acc[m], 0, 0, 0);
      }
    }
  }
#pragma unroll
  for (int m = 0; m < 4; ++m)
#pragma unroll
    for (int j = 0; j < 4; ++j) {
      int bb = m * 16 + (lane >> 4) * 4 + j;
      gl[w][bb][lane & 15] = acc[m][j];
    }
  __syncthreads();
#pragma unroll
  for (int p = 0; p < 4; ++p) {
    int idx = p * 256 + tid;
    int bb = idx >> 4, jj = idx & 15;
    const unsigned short* xp = Xpre + (size_t)bb * xstride + j0 + jj;
    float gi = gl[0][bb][jj] + bf2f(xp[0]);
    float gf = gl[1][bb][jj] + bf2f(xp[Hv]);
    float gg = gl[2][bb][jj] + bf2f(xp[2 * Hv]);
    float go = gl[3][bb][jj] + bf2f(xp[3 * Hv]);
    float co = cbuf[bb * Hv + j0 + jj];
    float cn = sigm(gf) * co + sigm(gi) * tanhf(gg);
    float hn = sigm(go) * tanhf(cn);
    cbuf[bb * Hv + j0 + jj] = cn;
    Hout[(size_t)bb * ostride + j0 + jj] = f2bf(hn);
  }
}

// ---------------- batched attention: block per (b,t) row ----------------
__global__ __launch_bounds__(256) void attn_kernel(const unsigned short* __restrict__ Hdec,
                                                   const unsigned short* __restrict__ Henc,
                                                   const int* __restrict__ src_nums,
                                                   unsigned short* __restrict__ cat) {
  __shared__ float hd[Hv];
  __shared__ float sc[Sv];
  __shared__ float al[Sv];
  __shared__ float inv_s;
  int r = blockIdx.x;      // b*T + t
  int b = r >> 6;
  int tid = threadIdx.x;
#pragma unroll
  for (int i = 0; i < 4; ++i) {
    int j = i * 256 + tid;
    hd[j] = bf2f(Hdec[(size_t)r * Hv + j]);
  }
  __syncthreads();
  int lane = tid & 63, w = tid >> 6;
  {
    int s = w * 32 + (lane >> 1);
    int half = lane & 1;
    const unsigned short* hrow = Henc + ((size_t)(b * Sv + s)) * Hv + half * 512;
    const float* hdp = hd + half * 512;
    float ps = 0.f;
#pragma unroll 8
    for (int j = 0; j < 512; j += 2) {
      unsigned int u = *(const unsigned int*)&hrow[j];
      ps += hdp[j] * bf2f((unsigned short)(u & 0xFFFFu));
      ps += hdp[j + 1] * bf2f((unsigned short)(u >> 16));
    }
    ps += __shfl_xor(ps, 1);
    if (half == 0) {
      float v = ps * 0.03125f;  // 1/sqrt(1024)
      if (src_nums[b * Sv + s] == 0) v = -1e30f;
      sc[s] = v;
    }
  }
  __syncthreads();
  if (w == 0) {
    float v0 = sc[lane], v1 = sc[lane + 64];
    float mx = fmaxf(v0, v1);
#pragma unroll
    for (int o = 1; o < 64; o <<= 1) mx = fmaxf(mx, __shfl_xor(mx, o));
    float e0 = __expf(v0 - mx), e1 = __expf(v1 - mx);
    al[lane] = e0;
    al[lane + 64] = e1;
    float ss = e0 + e1;
#pragma unroll
    for (int o = 1; o < 64; o <<= 1) ss += __shfl_xor(ss, o);
    if (lane == 0) inv_s = 1.f / ss;
  }
  __syncthreads();
  float inv = inv_s;
  int j0 = tid * 4;
  float a0 = 0, a1 = 0, a2 = 0, a3 = 0;
  for (int s2 = 0; s2 < Sv; ++s2) {
    float a = al[s2];
    const unsigned short* hr = Henc + ((size_t)(b * Sv + s2)) * Hv + j0;
    ushort4 u = *(const ushort4*)hr;
    a0 += a * bf2f(u.x);
    a1 += a * bf2f(u.y);
    a2 += a * bf2f(u.z);
    a3 += a * bf2f(u.w);
  }
  ushort4 o4;
  o4.x = f2bf(a0 * inv); o4.y = f2bf(a1 * inv); o4.z = f2bf(a2 * inv); o4.w = f2bf(a3 * inv);
  *(ushort4*)&cat[(size_t)r * 2048 + j0] = o4;
  ushort4 h4;
  h4.x = f2bf(hd[j0]); h4.y = f2bf(hd[j0 + 1]); h4.z = f2bf(hd[j0 + 2]); h4.w = f2bf(hd[j0 + 3]);
  *(ushort4*)&cat[(size_t)r * 2048 + 1024 + j0] = h4;
}

// ---------------- loss: per-row lse - tgt_logit, then deterministic sum ----------------
__global__ __launch_bounds__(256) void loss_row(const float* __restrict__ partial,
                                                const float* __restrict__ tlog,
                                                const int* __restrict__ tgt,
                                                float* __restrict__ rowloss) {
  int r = blockIdx.x * 256 + threadIdx.x;  // 4096 rows
  float ssum = 0.f;
  for (int c = 0; c < Vv / 64; ++c) ssum += partial[(size_t)c * (Bv * Tv) + r];
  float l = logf(ssum) - tlog[r];
  rowloss[r] = (tgt[r] != 0) ? l : 0.f;
}

__global__ __launch_bounds__(256) void loss_final(const float* __restrict__ rowloss,
                                                  float* __restrict__ out) {
  __shared__ float red[256];
  int tid = threadIdx.x;
  float s = 0.f;
  for (int i = tid; i < Bv * Tv; i += 256) s += rowloss[i];
  red[tid] = s;
  __syncthreads();
  for (int o = 128; o > 0; o >>= 1) {
    if (tid < o) red[tid] += red[tid + o];
    __syncthreads();
  }
  if (tid == 0) out[0] = red[0];
}

extern "C" void kernel_launch(void* const* d_in, const int* in_sizes, int n_in,
                              void* d_out, int out_size, void* d_ws, size_t ws_size,
                              hipStream_t stream) {
  (void)in_sizes; (void)n_in; (void)out_size; (void)ws_size;
  const int* src_nums = (const int*)d_in[0];
  const int* tgt_nums = (const int*)d_in[1];
  const float* src_emb = (const float*)d_in[2];
  const float* tgt_emb = (const float*)d_in[3];
  const float* eWx1 = (const float*)d_in[4];
  const float* eWh1 = (const float*)d_in[5];
  const float* eb1  = (const float*)d_in[6];
  const float* eWx2 = (const float*)d_in[7];
  const float* eWh2 = (const float*)d_in[8];
  const float* eb2  = (const float*)d_in[9];
  const float* dWx  = (const float*)d_in[10];
  const float* dWh  = (const float*)d_in[11];
  const float* db   = (const float*)d_in[12];
  const float* h0   = (const float*)d_in[13];
  const float* m0   = (const float*)d_in[14];
  const float* Wt   = (const float*)d_in[15];
  const float* bt   = (const float*)d_in[16];
  const float* Wo   = (const float*)d_in[17];
  const float* bo   = (const float*)d_in[18];

  char* base = (char*)d_ws;
  size_t off = 0;
  auto alloc = [&](size_t bytes) -> void* {
    void* r = base + off;
    off += (bytes + 255) & ~(size_t)255;
    return r;
  };
  unsigned short* WX1T = (unsigned short*)alloc((size_t)H4v * Hv * 2);
  unsigned short* WH1T = (unsigned short*)alloc((size_t)H4v * Hv * 2);
  unsigned short* WX2T = (unsigned short*)alloc((size_t)H4v * Hv * 2);
  unsigned short* WH2T = (unsigned short*)alloc((size_t)H4v * Hv * 2);
  unsigned short* DWXT = (unsigned short*)alloc((size_t)H4v * Hv * 2);
  unsigned short* DWHT = (unsigned short*)alloc((size_t)H4v * Hv * 2);
  unsigned short* WTT  = (unsigned short*)alloc((size_t)Hv * 2048 * 2);
  unsigned short* WOT  = (unsigned short*)alloc((size_t)Vv * Hv * 2);
  unsigned short* SEMB = (unsigned short*)alloc((size_t)Bv * Sv * Hv * 2);
  unsigned short* TEMB = (unsigned short*)alloc((size_t)Bv * Tv * Hv * 2);
  unsigned short* XPRE = (unsigned short*)alloc((size_t)Bv * Sv * H4v * 2);  // reused enc1/enc2/dec
  unsigned short* H1SEQ = (unsigned short*)alloc((size_t)Bv * Sv * Hv * 2);
  unsigned short* HENC  = (unsigned short*)alloc((size_t)Bv * Sv * Hv * 2);
  unsigned short* HDEC  = (unsigned short*)alloc((size_t)Bv * Tv * Hv * 2);
  unsigned short* CAT   = (unsigned short*)alloc((size_t)Bv * Tv * 2048 * 2);
  unsigned short* ZBUF  = (unsigned short*)alloc((size_t)Bv * Tv * Hv * 2);
  float* PART  = (float*)alloc((size_t)(Vv / 64) * (Bv * Tv) * 4);
  float* TLOG  = (float*)alloc((size_t)(Bv * Tv) * 4);
  float* RLOSS = (float*)alloc((size_t)(Bv * Tv) * 4);
  unsigned short* ZH = (unsigned short*)alloc((size_t)Bv * Hv * 2);
  float* C1 = (float*)alloc((size_t)Bv * Hv * 4);
  float* C2 = (float*)alloc((size_t)Bv * Hv * 4);
  float* MD = (float*)alloc((size_t)Bv * Hv * 4);

  dim3 tb(32, 8);
  transpose_bf16<<<dim3(H4v / 32, Hv / 32), tb, 0, stream>>>(eWx1, WX1T, Hv, H4v);
  transpose_bf16<<<dim3(H4v / 32, Hv / 32), tb, 0, stream>>>(eWh1, WH1T, Hv, H4v);
  transpose_bf16<<<dim3(H4v / 32, Hv / 32), tb, 0, stream>>>(eWx2, WX2T, Hv, H4v);
  transpose_bf16<<<dim3(H4v / 32, Hv / 32), tb, 0, stream>>>(eWh2, WH2T, Hv, H4v);
  transpose_bf16<<<dim3(H4v / 32, Hv / 32), tb, 0, stream>>>(dWx, DWXT, Hv, H4v);
  transpose_bf16<<<dim3(H4v / 32, Hv / 32), tb, 0, stream>>>(dWh, DWHT, Hv, H4v);
  transpose_bf16<<<dim3(Hv / 32, 2048 / 32), tb, 0, stream>>>(Wt, WTT, 2048, Hv);
  transpose_bf16<<<dim3(Vv / 32, Hv / 32), tb, 0, stream>>>(Wo, WOT, Hv, Vv);

  init_k<<<256, 256, 0, stream>>>(ZH, C1, C2, MD, HDEC, h0, m0);
  gather_emb<<<Bv * Sv, 256, 0, stream>>>(src_nums, src_emb, SEMB);
  gather_emb<<<Bv * Tv, 256, 0, stream>>>(tgt_nums, tgt_emb, TEMB);

  // ---- encoder layer 1 ----
  gemm128<1><<<dim3(H4v / 128, (Bv * Sv) / 128), 256, 0, stream>>>(
      SEMB, WX1T, eb1, XPRE, Bv * Sv, H4v, Hv, nullptr, nullptr, nullptr);
  for (int t = 0; t < Sv; ++t) {
    const unsigned short* hp = (t == 0) ? ZH : H1SEQ + (size_t)(t - 1) * Hv;
    int hstr = (t == 0) ? Hv : Sv * Hv;
    lstm_step<<<64, 256, 0, stream>>>(hp, hstr, XPRE + (size_t)t * H4v, Sv * H4v, WH1T, C1,
                                      H1SEQ + (size_t)t * Hv, Sv * Hv);
  }
  // ---- encoder layer 2 ----
  gemm128<1><<<dim3(H4v / 128, (Bv * Sv) / 128), 256, 0, stream>>>(
      H1SEQ, WX2T, eb2, XPRE, Bv * Sv, H4v, Hv, nullptr, nullptr, nullptr);
  for (int t = 0; t < Sv; ++t) {
    const unsigned short* hp = (t == 0) ? ZH : HENC + (size_t)(t - 1) * Hv;
    int hstr = (t == 0) ? Hv : Sv * Hv;
    lstm_step<<<64, 256, 0, stream>>>(hp, hstr, XPRE + (size_t)t * H4v, Sv * H4v, WH2T, C2,
                                      HENC + (size_t)t * Hv, Sv * Hv);
  }
  // ---- decoder recurrence (h_t needed for attention is PRE-update) ----
  gemm128<1><<<dim3(H4v / 128, (Bv * Tv) / 128), 256, 0, stream>>>(
      TEMB, DWXT, db, XPRE, Bv * Tv, H4v, Hv, nullptr, nullptr, nullptr);
  for (int t = 0; t < Tv - 1; ++t) {
    lstm_step<<<64, 256, 0, stream>>>(HDEC + (size_t)t * Hv, Tv * Hv, XPRE + (size_t)t * H4v,
                                      Tv * H4v, DWHT, MD, HDEC + (size_t)(t + 1) * Hv, Tv * Hv);
  }
  // ---- batched attention + concat ----
  attn_kernel<<<Bv * Tv, 256, 0, stream>>>(HDEC, HENC, src_nums, CAT);
  // ---- z = tanh(cat @ Wt + bt) ----
  gemm128<2><<<dim3(Hv / 128, (Bv * Tv) / 128), 256, 0, stream>>>(
      CAT, WTT, bt, ZBUF, Bv * Tv, Hv, 2048, nullptr, nullptr, nullptr);
  // ---- fused logits GEMM: exp-sum partials + target logit gather ----
  gemm128<3><<<dim3(Vv / 128, (Bv * Tv) / 128), 256, 0, stream>>>(
      ZBUF, WOT, bo, nullptr, Bv * Tv, Vv, Hv, PART, TLOG, tgt_nums);
  // ---- loss ----
  loss_row<<<(Bv * Tv) / 256, 256, 0, stream>>>(PART, TLOG, tgt_nums, RLOSS);
  loss_final<<<1, 256, 0, stream>>>(RLOSS, (float*)d_out);
}

// Round 2
// 3071.679 us; speedup vs baseline: 1.6427x; 1.6427x over previous
//
#include <hip/hip_runtime.h>

// Seq2seq LSTM: 2-layer encoder (S=128) + attention decoder (T=64), B=64, H=1024, V=32000.
// All x@Wx precomputed as big MFMA GEMMs; the 319 sequential h@Wh steps run inside ONE
// persistent 256-block kernel (enc-L1 / enc-L2 / decoder concurrently) with a hand-rolled
// device-scope grid barrier; h exchanged via sc0sc1 cache-bypass ops so weights stay in L2.

#define Bv 64
#define Sv 128
#define Tv 64
#define Hv 1024
#define H4v 4096
#define Vv 32000
#define NBLK 256
#define ROUNDS 129

using bf16x8 = __attribute__((ext_vector_type(8))) short;
using f32x4  = __attribute__((ext_vector_type(4))) float;

typedef __attribute__((address_space(1))) const void gvoid_t;
typedef __attribute__((address_space(3))) void lvoid_t;

__device__ __forceinline__ void gload16(const void* g, void* l) {
  __builtin_amdgcn_global_load_lds((gvoid_t*)g, (lvoid_t*)l, 16, 0, 0);
}

__device__ __forceinline__ float bf2f(unsigned short u) {
  unsigned int v = ((unsigned int)u) << 16;
  return __uint_as_float(v);
}
__device__ __forceinline__ unsigned short f2bf(float f) {
  unsigned int u = __float_as_uint(f);
  return (unsigned short)((u + 0x7FFFu + ((u >> 16) & 1u)) >> 16);
}
__device__ __forceinline__ float sigm(float x) { return 1.f / (1.f + __expf(-x)); }
__device__ __forceinline__ float tanh_f(float x) {
  float ax = fabsf(x);
  float e = __expf(-2.f * ax);
  float t = (1.f - e) / (1.f + e);
  return copysignf(t, x);
}

// cache-bypass (coherence-point) 16B load / 8B,4B stores
__device__ __forceinline__ int4 ldx4_cv(const unsigned short* p) {
  int4 r;
  asm volatile("global_load_dwordx4 %0, %1, off sc0 sc1" : "=v"(r) : "v"(p));
  return r;
}
__device__ __forceinline__ void stx2_wt(unsigned short* p, int2 v) {
  asm volatile("global_store_dwordx2 %0, %1, off sc0 sc1" :: "v"(p), "v"(v) : "memory");
}
__device__ __forceinline__ void st1_wt(unsigned short* p, int v) {
  asm volatile("global_store_dword %0, %1, off sc0 sc1" :: "v"(p), "v"(v) : "memory");
}

// ---------------- transpose + fp32->bf16 convert: out[c][r] (row length ostride) ----------------
__global__ __launch_bounds__(256) void transpose_bf16(const float* __restrict__ in,
                                                      unsigned short* __restrict__ out,
                                                      int R, int C, int ostride) {
  __shared__ float tile[32][33];
  int tx = threadIdx.x, ty = threadIdx.y;
  int c0 = blockIdx.x * 32, r0 = blockIdx.y * 32;
#pragma unroll
  for (int i = 0; i < 32; i += 8)
    tile[ty + i][tx] = in[(size_t)(r0 + ty + i) * C + c0 + tx];
  __syncthreads();
#pragma unroll
  for (int i = 0; i < 32; i += 8)
    out[(size_t)(c0 + ty + i) * ostride + r0 + tx] = f2bf(tile[tx][ty + i]);
}

// ---------------- embedding gather (fp32 table -> bf16 rows) ----------------
__global__ __launch_bounds__(256) void gather_emb(const int* __restrict__ toks,
                                                  const float* __restrict__ emb,
                                                  unsigned short* __restrict__ dst) {
  int r = blockIdx.x, tid = threadIdx.x;
  int tok = toks[r];
  int j = tid * 4;
  float4 v = *(const float4*)&emb[(size_t)tok * Hv + j];
  ushort4 o;
  o.x = f2bf(v.x); o.y = f2bf(v.y); o.z = f2bf(v.z); o.w = f2bf(v.w);
  *(ushort4*)&dst[(size_t)r * Hv + j] = o;
}

// ---------------- init: zero-h buffer, decoder h0 broadcast, barrier counters ----------------
__global__ __launch_bounds__(256) void init_k(unsigned short* __restrict__ zh,
                                              unsigned short* __restrict__ Hdec,
                                              const float* __restrict__ h0,
                                              int* __restrict__ bar) {
  int idx = blockIdx.x * 256 + threadIdx.x;  // 65536 = 64*1024
  int j = idx & (Hv - 1);
  int b = idx >> 10;
  zh[idx] = 0;
  Hdec[(size_t)(b * Tv) * Hv + j] = f2bf(h0[j]);
  if (idx < 256) bar[idx] = 0;
}

// ---------------- generic 128x128 MFMA GEMM, B pre-transposed [N][K] bf16 ----------------
// EPI: 1 = bf16 out (+bias), 2 = tanh -> bf16 (+bias), 3 = fused logits (exp-sum partials + tgt gather)
template <int EPI>
__global__ __launch_bounds__(256) void gemm128(const unsigned short* __restrict__ A,
                                               const unsigned short* __restrict__ Bt,
                                               const float* __restrict__ bias,
                                               unsigned short* __restrict__ Cbf,
                                               int M, int N, int K,
                                               float* __restrict__ partial,
                                               float* __restrict__ tlog,
                                               const int* __restrict__ tgt) {
  __shared__ unsigned short As[128 * 64];
  __shared__ unsigned short Bs[128 * 64];
  int tid = threadIdx.x, lane = tid & 63, w = tid >> 6;
  int wr = w >> 1, wc = w & 1;
  int m0 = blockIdx.y * 128, n0 = blockIdx.x * 128;
  f32x4 acc[4][4] = {};
  for (int k0 = 0; k0 < K; k0 += 64) {
    __syncthreads();
#pragma unroll
    for (int q = 0; q < 4; ++q) {
      int idx = q * 256 + tid;
      int row = idx >> 3, phys = idx & 7, lg = phys ^ (row & 7);
      gload16(A + (size_t)(m0 + row) * K + k0 + lg * 8, &As[idx * 8]);
    }
#pragma unroll
    for (int q = 0; q < 4; ++q) {
      int idx = q * 256 + tid;
      int row = idx >> 3, phys = idx & 7, lg = phys ^ (row & 7);
      gload16(Bt + (size_t)(n0 + row) * K + k0 + lg * 8, &Bs[idx * 8]);
    }
    __syncthreads();
#pragma unroll
    for (int kk = 0; kk < 64; kk += 32) {
      int lgb = (kk >> 3) + (lane >> 4);
      bf16x8 af[4], bfr[4];
#pragma unroll
      for (int m = 0; m < 4; ++m) {
        int row = wr * 64 + m * 16 + (lane & 15);
        af[m] = *(const bf16x8*)&As[(row * 8 + (lgb ^ (row & 7))) * 8];
      }
#pragma unroll
      for (int n = 0; n < 4; ++n) {
        int row = wc * 64 + n * 16 + (lane & 15);
        bfr[n] = *(const bf16x8*)&Bs[(row * 8 + (lgb ^ (row & 7))) * 8];
      }
#pragma unroll
      for (int m = 0; m < 4; ++m)
#pragma unroll
        for (int n = 0; n < 4; ++n)
          acc[m][n] = __builtin_amdgcn_mfma_f32_16x16x32_bf16(af[m], bfr[n], acc[m][n], 0, 0, 0);
    }
  }
  if (EPI != 3) {
#pragma unroll
    for (int m = 0; m < 4; ++m)
#pragma unroll
      for (int n = 0; n < 4; ++n) {
        int col = n0 + wc * 64 + n * 16 + (lane & 15);
        float bv = bias[col];
#pragma unroll
        for (int j = 0; j < 4; ++j) {
          int row = m0 + wr * 64 + m * 16 + (lane >> 4) * 4 + j;
          float v = acc[m][n][j] + bv;
          if (EPI == 2) v = tanhf(v);
          Cbf[(size_t)row * N + col] = f2bf(v);
        }
      }
  } else {
    int chunk = (n0 + wc * 64) >> 6;  // 64-col chunk owned by this wave
#pragma unroll
    for (int m = 0; m < 4; ++m)
#pragma unroll
      for (int j = 0; j < 4; ++j) {
        int row = m0 + wr * 64 + m * 16 + (lane >> 4) * 4 + j;
        int tv = tgt[row];
        float se = 0.f;
#pragma unroll
        for (int n = 0; n < 4; ++n) {
          int col = n0 + wc * 64 + n * 16 + (lane & 15);
          float v = acc[m][n][j] + bias[col];
          se += __expf(v);  // logits are O(1): no max-subtraction needed
          if (col == tv) tlog[row] = v;
        }
        se += __shfl_xor(se, 1);
        se += __shfl_xor(se, 2);
        se += __shfl_xor(se, 4);
        se += __shfl_xor(se, 8);
        if ((lane & 15) == 0) partial[(size_t)chunk * M + row] = se;
      }
  }
}

// ---------------- persistent LSTM chain kernel ----------------
__device__ __forceinline__ void gridbar(int* bar, int target, int tid, int bid) {
  __syncthreads();
  if (tid == 0)
    __hip_atomic_fetch_add(&bar[(bid & 7) * 32], 1, __ATOMIC_RELAXED, __HIP_MEMORY_SCOPE_AGENT);
  if (tid < 8) {
    int it = 0;
    while (true) {
      int s = __hip_atomic_load(&bar[tid * 32], __ATOMIC_RELAXED, __HIP_MEMORY_SCOPE_AGENT);
      s += __shfl_xor(s, 1);
      s += __shfl_xor(s, 2);
      s += __shfl_xor(s, 4);
      if (s >= target) break;
      __builtin_amdgcn_s_sleep(1);
      if (++it > (1 << 18)) break;  // bounded: fail loud (wrong result), never hang
    }
  }
  __syncthreads();
}

// GRP 0 = enc layer1 (NF=4, K=1024), 1 = enc layer2 (NF=2, K=2048 stacked), 2 = decoder (NF=4, K=1024)
template <int NF, int KIT, int GRP>
__device__ __forceinline__ void run_group(
    int gid, int tid, const unsigned short* __restrict__ Wp, int Kdim,
    const unsigned short* __restrict__ XP, const float* __restrict__ eb2,
    const float* __restrict__ m0, const unsigned short* __restrict__ ZH,
    unsigned short* __restrict__ H1, unsigned short* __restrict__ HENC,
    unsigned short* __restrict__ HDEC, int* bar, float (&gl)[4][64][64], int bid) {
  const int lane = tid & 63, w = tid >> 6, l15 = lane & 15, l4 = lane >> 4;
  const int NC = NF * 4;
  const int j0 = gid * NC;
  int grow[NF];
#pragma unroll
  for (int n = 0; n < NF; ++n) {
    if (NF == 4) grow[n] = n * 1024 + j0 + l15;
    else         grow[n] = (2 * n + ((lane >> 3) & 1)) * 1024 + j0 + (lane & 7);
  }
  const int kw0 = w * (Kdim / 4);
  const int b_ = tid & 63;
  const int cb = (tid >> 6) * NF;
  float cst[NF];
  float br[4][NF];
#pragma unroll
  for (int e = 0; e < NF; ++e) cst[e] = (GRP == 2) ? m0[j0 + cb + e] : 0.f;
  if (GRP == 1) {
#pragma unroll
    for (int g = 0; g < 4; ++g)
#pragma unroll
      for (int e = 0; e < NF; ++e) br[g][e] = eb2[g * 1024 + j0 + cb + e];
  }

  for (int r = 0; r < ROUNDS; ++r) {
    bool active;
    int t;
    if (GRP == 0)      { active = (r < 128); t = r; }
    else if (GRP == 1) { active = (r >= 1);  t = r - 1; }
    else               { active = (r < 63);  t = r; }
    if (active) {
      const unsigned short* Aw;
      size_t asw;
      int kbase = kw0;
      if (GRP == 0) {
        Aw = (r == 0) ? ZH : H1 + (size_t)((r - 1) & 1) * (64 * 1024);
        asw = 1024;
      } else if (GRP == 2) {
        Aw = HDEC + (size_t)t * 1024;
        asw = (size_t)Tv * 1024;
      } else {
        if (w < 2) { Aw = H1 + (size_t)((r - 1) & 1) * (64 * 1024); asw = 1024; }
        else {
          kbase = kw0 - 1024;
          if (t == 0) { Aw = ZH; asw = 1024; }
          else { Aw = HENC + (size_t)(t - 1) * 1024; asw = (size_t)Sv * 1024; }
        }
      }
      ushort4 xg[4];
      if (GRP == 0) {
#pragma unroll
        for (int g = 0; g < 4; ++g)
          xg[g] = *(const ushort4*)(XP + ((size_t)b_ * Sv + t) * H4v + g * 1024 + j0 + cb);
      } else if (GRP == 2) {
#pragma unroll
        for (int g = 0; g < 4; ++g)
          xg[g] = *(const ushort4*)(XP + ((size_t)b_ * Tv + t) * H4v + g * 1024 + j0 + cb);
      }
      f32x4 acc[4][NF];
#pragma unroll
      for (int m = 0; m < 4; ++m)
#pragma unroll
        for (int n = 0; n < NF; ++n) acc[m][n] = (f32x4){0.f, 0.f, 0.f, 0.f};
      bf16x8 bfr[2][NF];
      int4 afr[2][4];
#pragma unroll
      for (int n = 0; n < NF; ++n)
        bfr[0][n] = *(const bf16x8*)(Wp + (size_t)grow[n] * Kdim + kw0 + l4 * 8);
#pragma unroll
      for (int m = 0; m < 4; ++m)
        afr[0][m] = ldx4_cv(Aw + (size_t)(m * 16 + l15) * asw + kbase + l4 * 8);
#pragma unroll
      for (int ki = 0; ki < KIT; ++ki) {
        const int cur = ki & 1, nxt = cur ^ 1;
        if (ki + 1 < KIT) {
#pragma unroll
          for (int n = 0; n < NF; ++n)
            bfr[nxt][n] = *(const bf16x8*)(Wp + (size_t)grow[n] * Kdim + kw0 + (ki + 1) * 32 + l4 * 8);
#pragma unroll
          for (int m = 0; m < 4; ++m)
            afr[nxt][m] = ldx4_cv(Aw + (size_t)(m * 16 + l15) * asw + kbase + (ki + 1) * 32 + l4 * 8);
          if (NF == 4) asm volatile("s_waitcnt vmcnt(8)" ::: "memory");
          else         asm volatile("s_waitcnt vmcnt(6)" ::: "memory");
        } else {
          asm volatile("s_waitcnt vmcnt(0)" ::: "memory");
        }
        __builtin_amdgcn_sched_barrier(0);
#pragma unroll
        for (int m = 0; m < 4; ++m)
#pragma unroll
          for (int n = 0; n < NF; ++n)
            acc[m][n] = __builtin_amdgcn_mfma_f32_16x16x32_bf16(
                *(const bf16x8*)&afr[cur][m], bfr[cur][n], acc[m][n], 0, 0, 0);
      }
      // cross-wave K-reduce through LDS (bank-swizzled: q ^ (row&31) -> 2-way max on reads)
#pragma unroll
      for (int m = 0; m < 4; ++m)
#pragma unroll
        for (int n = 0; n < NF; ++n)
#pragma unroll
          for (int j = 0; j < 4; ++j) {
            int bb = m * 16 + l4 * 4 + j;
            int q = n * 16 + l15;
            gl[w][bb][q ^ (bb & 31)] = acc[m][n][j];
          }
      __syncthreads();
      float G[4][NF];
#pragma unroll
      for (int g = 0; g < 4; ++g)
#pragma unroll
        for (int e = 0; e < NF; ++e) {
          int q = (NF == 4) ? (g * 16 + cb + e) : (g * 8 + cb + e);
          int qs = q ^ (b_ & 31);
          G[g][e] = gl[0][b_][qs] + gl[1][b_][qs] + gl[2][b_][qs] + gl[3][b_][qs];
        }
      unsigned short ho[NF];
#pragma unroll
      for (int e = 0; e < NF; ++e) {
        float gi, gf, gg, go;
        if (GRP == 1) {
          gi = G[0][e] + br[0][e]; gf = G[1][e] + br[1][e];
          gg = G[2][e] + br[2][e]; go = G[3][e] + br[3][e];
        } else {
          gi = G[0][e] + bf2f(((const unsigned short*)&xg[0])[e]);
          gf = G[1][e] + bf2f(((const unsigned short*)&xg[1])[e]);
          gg = G[2][e] + bf2f(((const unsigned short*)&xg[2])[e]);
          go = G[3][e] + bf2f(((const unsigned short*)&xg[3])[e]);
        }
        float cn = sigm(gf) * cst[e] + sigm(gi) * tanh_f(gg);
        float hn = sigm(go) * tanh_f(cn);
        cst[e] = cn;
        ho[e] = f2bf(hn);
      }
      if (GRP == 0) {
        int2 pk;
        pk.x = (int)ho[0] | ((int)ho[1] << 16);
        pk.y = (int)ho[2] | ((int)ho[3] << 16);
        stx2_wt(H1 + (size_t)(r & 1) * (64 * 1024) + b_ * 1024 + j0 + cb, pk);
      } else if (GRP == 1) {
        int pk = (int)ho[0] | ((int)ho[1] << 16);
        st1_wt(HENC + ((size_t)b_ * Sv + t) * 1024 + j0 + cb, pk);
      } else {
        int2 pk;
        pk.x = (int)ho[0] | ((int)ho[1] << 16);
        pk.y = (int)ho[2] | ((int)ho[3] << 16);
        stx2_wt(HDEC + ((size_t)b_ * Tv + (t + 1)) * 1024 + j0 + cb, pk);
      }
      asm volatile("s_waitcnt vmcnt(0)" ::: "memory");  // drain h stores before signaling
    }
    gridbar(bar, NBLK * (r + 1), tid, bid);
  }
}

__global__ __launch_bounds__(256, 1) void chain_kernel(
    const unsigned short* __restrict__ W1T, const unsigned short* __restrict__ W2S,
    const unsigned short* __restrict__ WDT, const unsigned short* __restrict__ XP1,
    const unsigned short* __restrict__ XPD, const float* __restrict__ eb2,
    const float* __restrict__ m0, const unsigned short* __restrict__ ZH,
    unsigned short* __restrict__ H1, unsigned short* __restrict__ HENC,
    unsigned short* __restrict__ HDEC, int* bar) {
  __shared__ float gl[4][64][64];
  int bid = blockIdx.x, tid = threadIdx.x;
  if (bid < 64)
    run_group<4, 8, 0>(bid, tid, W1T, 1024, XP1, eb2, m0, ZH, H1, HENC, HDEC, bar, gl, bid);
  else if (bid < 192)
    run_group<2, 16, 1>(bid - 64, tid, W2S, 2048, nullptr, eb2, m0, ZH, H1, HENC, HDEC, bar, gl, bid);
  else
    run_group<4, 8, 2>(bid - 192, tid, WDT, 1024, XPD, eb2, m0, ZH, H1, HENC, HDEC, bar, gl, bid);
}

// ---------------- batched attention: block per (b,t) row ----------------
__global__ __launch_bounds__(256) void attn_kernel(const unsigned short* __restrict__ Hdec,
                                                   const unsigned short* __restrict__ Henc,
                                                   const int* __restrict__ src_nums,
                                                   unsigned short* __restrict__ cat) {
  __shared__ float hd[Hv];
  __shared__ float sc[Sv];
  __shared__ float al[Sv];
  __shared__ float inv_s;
  int r = blockIdx.x;  // b*T + t
  int b = r >> 6;
  int tid = threadIdx.x;
#pragma unroll
  for (int i = 0; i < 4; ++i) {
    int j = i * 256 + tid;
    hd[j] = bf2f(Hdec[(size_t)r * Hv + j]);
  }
  __syncthreads();
  int lane = tid & 63, w = tid >> 6;
  {
    int s = w * 32 + (lane >> 1);
    int half = lane & 1;
    const unsigned short* hrow = Henc + ((size_t)(b * Sv + s)) * Hv + half * 512;
    const float* hdp = hd + half * 512;
    float ps = 0.f;
#pragma unroll 8
    for (int j = 0; j < 512; j += 2) {
      unsigned int u = *(const unsigned int*)&hrow[j];
      ps += hdp[j] * bf2f((unsigned short)(u & 0xFFFFu));
      ps += hdp[j + 1] * bf2f((unsigned short)(u >> 16));
    }
    ps += __shfl_xor(ps, 1);
    if (half == 0) {
      float v = ps * 0.03125f;  // 1/sqrt(1024)
      if (src_nums[b * Sv + s] == 0) v = -1e30f;
      sc[s] = v;
    }
  }
  __syncthreads();
  if (w == 0) {
    float v0 = sc[lane], v1 = sc[lane + 64];
    float mx = fmaxf(v0, v1);
#pragma unroll
    for (int o = 1; o < 64; o <<= 1) mx = fmaxf(mx, __shfl_xor(mx, o));
    float e0 = __expf(v0 - mx), e1 = __expf(v1 - mx);
    al[lane] = e0;
    al[lane + 64] = e1;
    float ss = e0 + e1;
#pragma unroll
    for (int o = 1; o < 64; o <<= 1) ss += __shfl_xor(ss, o);
    if (lane == 0) inv_s = 1.f / ss;
  }
  __syncthreads();
  float inv = inv_s;
  int j0 = tid * 4;
  float a0 = 0, a1 = 0, a2 = 0, a3 = 0;
  for (int s2 = 0; s2 < Sv; ++s2) {
    float a = al[s2];
    const unsigned short* hr = Henc + ((size_t)(b * Sv + s2)) * Hv + j0;
    ushort4 u = *(const ushort4*)hr;
    a0 += a * bf2f(u.x);
    a1 += a * bf2f(u.y);
    a2 += a * bf2f(u.z);
    a3 += a * bf2f(u.w);
  }
  ushort4 o4;
  o4.x = f2bf(a0 * inv); o4.y = f2bf(a1 * inv); o4.z = f2bf(a2 * inv); o4.w = f2bf(a3 * inv);
  *(ushort4*)&cat[(size_t)r * 2048 + j0] = o4;
  ushort4 h4;
  h4.x = f2bf(hd[j0]); h4.y = f2bf(hd[j0 + 1]); h4.z = f2bf(hd[j0 + 2]); h4.w = f2bf(hd[j0 + 3]);
  *(ushort4*)&cat[(size_t)r * 2048 + 1024 + j0] = h4;
}

// ---------------- loss: per-row lse - tgt_logit, then deterministic sum ----------------
__global__ __launch_bounds__(256) void loss_row(const float* __restrict__ partial,
                                                const float* __restrict__ tlog,
                                                const int* __restrict__ tgt,
                                                float* __restrict__ rowloss) {
  int r = blockIdx.x * 256 + threadIdx.x;  // 4096 rows
  float ssum = 0.f;
  for (int c = 0; c < Vv / 64; ++c) ssum += partial[(size_t)c * (Bv * Tv) + r];
  float l = logf(ssum) - tlog[r];
  rowloss[r] = (tgt[r] != 0) ? l : 0.f;
}

__global__ __launch_bounds__(256) void loss_final(const float* __restrict__ rowloss,
                                                  float* __restrict__ out) {
  __shared__ float red[256];
  int tid = threadIdx.x;
  float s = 0.f;
  for (int i = tid; i < Bv * Tv; i += 256) s += rowloss[i];
  red[tid] = s;
  __syncthreads();
  for (int o = 128; o > 0; o >>= 1) {
    if (tid < o) red[tid] += red[tid + o];
    __syncthreads();
  }
  if (tid == 0) out[0] = red[0];
}

extern "C" void kernel_launch(void* const* d_in, const int* in_sizes, int n_in,
                              void* d_out, int out_size, void* d_ws, size_t ws_size,
                              hipStream_t stream) {
  (void)in_sizes; (void)n_in; (void)out_size; (void)ws_size;
  const int* src_nums = (const int*)d_in[0];
  const int* tgt_nums = (const int*)d_in[1];
  const float* src_emb = (const float*)d_in[2];
  const float* tgt_emb = (const float*)d_in[3];
  const float* eWx1 = (const float*)d_in[4];
  const float* eWh1 = (const float*)d_in[5];
  const float* eb1  = (const float*)d_in[6];
  const float* eWx2 = (const float*)d_in[7];
  const float* eWh2 = (const float*)d_in[8];
  const float* eb2  = (const float*)d_in[9];
  const float* dWx  = (const float*)d_in[10];
  const float* dWh  = (const float*)d_in[11];
  const float* db   = (const float*)d_in[12];
  const float* h0   = (const float*)d_in[13];
  const float* m0   = (const float*)d_in[14];
  const float* Wt   = (const float*)d_in[15];
  const float* bt   = (const float*)d_in[16];
  const float* Wo   = (const float*)d_in[17];
  const float* bo   = (const float*)d_in[18];

  char* base = (char*)d_ws;
  size_t off = 0;
  auto alloc = [&](size_t bytes) -> void* {
    void* r = base + off;
    off += (bytes + 255) & ~(size_t)255;
    return r;
  };
  unsigned short* WX1T = (unsigned short*)alloc((size_t)H4v * Hv * 2);
  unsigned short* W1T  = (unsigned short*)alloc((size_t)H4v * Hv * 2);      // eWh1^T
  unsigned short* W2S  = (unsigned short*)alloc((size_t)H4v * 2048 * 2);    // [Wx2;Wh2] stacked-K
  unsigned short* DWXT = (unsigned short*)alloc((size_t)H4v * Hv * 2);
  unsigned short* WDT  = (unsigned short*)alloc((size_t)H4v * Hv * 2);      // dWh^T
  unsigned short* WTT  = (unsigned short*)alloc((size_t)Hv * 2048 * 2);
  unsigned short* WOT  = (unsigned short*)alloc((size_t)Vv * Hv * 2);
  unsigned short* SEMB = (unsigned short*)alloc((size_t)Bv * Sv * Hv * 2);
  unsigned short* TEMB = (unsigned short*)alloc((size_t)Bv * Tv * Hv * 2);
  unsigned short* XP1  = (unsigned short*)alloc((size_t)Bv * Sv * H4v * 2);
  unsigned short* XPD  = (unsigned short*)alloc((size_t)Bv * Tv * H4v * 2);
  unsigned short* HENC = (unsigned short*)alloc((size_t)Bv * Sv * Hv * 2);
  unsigned short* HDEC = (unsigned short*)alloc((size_t)Bv * Tv * Hv * 2);
  unsigned short* H1   = (unsigned short*)alloc((size_t)2 * Bv * Hv * 2);
  unsigned short* ZH   = (unsigned short*)alloc((size_t)Bv * Hv * 2);
  unsigned short* CAT  = (unsigned short*)alloc((size_t)Bv * Tv * 2048 * 2);
  unsigned short* ZBUF = (unsigned short*)alloc((size_t)Bv * Tv * Hv * 2);
  float* PART  = (float*)alloc((size_t)(Vv / 64) * (Bv * Tv) * 4);
  float* TLOG  = (float*)alloc((size_t)(Bv * Tv) * 4);
  float* RLOSS = (float*)alloc((size_t)(Bv * Tv) * 4);
  int* BAR     = (int*)alloc(256 * 4);

  dim3 tb(32, 8);
  transpose_bf16<<<dim3(H4v / 32, Hv / 32), tb, 0, stream>>>(eWx1, WX1T, Hv, H4v, Hv);
  transpose_bf16<<<dim3(H4v / 32, Hv / 32), tb, 0, stream>>>(eWh1, W1T, Hv, H4v, Hv);
  transpose_bf16<<<dim3(H4v / 32, Hv / 32), tb, 0, stream>>>(eWx2, W2S, Hv, H4v, 2048);
  transpose_bf16<<<dim3(H4v / 32, Hv / 32), tb, 0, stream>>>(eWh2, W2S + 1024, Hv, H4v, 2048);
  transpose_bf16<<<dim3(H4v / 32, Hv / 32), tb, 0, stream>>>(dWx, DWXT, Hv, H4v, Hv);
  transpose_bf16<<<dim3(H4v / 32, Hv / 32), tb, 0, stream>>>(dWh, WDT, Hv, H4v, Hv);
  transpose_bf16<<<dim3(Hv / 32, 2048 / 32), tb, 0, stream>>>(Wt, WTT, 2048, Hv, 2048);
  transpose_bf16<<<dim3(Vv / 32, Hv / 32), tb, 0, stream>>>(Wo, WOT, Hv, Vv, Hv);

  init_k<<<256, 256, 0, stream>>>(ZH, HDEC, h0, BAR);
  gather_emb<<<Bv * Sv, 256, 0, stream>>>(src_nums, src_emb, SEMB);
  gather_emb<<<Bv * Tv, 256, 0, stream>>>(tgt_nums, tgt_emb, TEMB);

  // ---- precompute x@Wx (+bias) for enc layer 1 and decoder ----
  gemm128<1><<<dim3(H4v / 128, (Bv * Sv) / 128), 256, 0, stream>>>(
      SEMB, WX1T, eb1, XP1, Bv * Sv, H4v, Hv, nullptr, nullptr, nullptr);
  gemm128<1><<<dim3(H4v / 128, (Bv * Tv) / 128), 256, 0, stream>>>(
      TEMB, DWXT, db, XPD, Bv * Tv, H4v, Hv, nullptr, nullptr, nullptr);

  // ---- all 319 recurrent steps in one persistent kernel ----
  chain_kernel<<<NBLK, 256, 0, stream>>>(W1T, W2S, WDT, XP1, XPD, eb2, m0, ZH, H1, HENC, HDEC, BAR);

  // ---- batched attention + concat ----
  attn_kernel<<<Bv * Tv, 256, 0, stream>>>(HDEC, HENC, src_nums, CAT);
  // ---- z = tanh(cat @ Wt + bt) ----
  gemm128<2><<<dim3(Hv / 128, (Bv * Tv) / 128), 256, 0, stream>>>(
      CAT, WTT, bt, ZBUF, Bv * Tv, Hv, 2048, nullptr, nullptr, nullptr);
  // ---- fused logits GEMM: exp-sum partials + target logit gather ----
  gemm128<3><<<dim3(Vv / 128, (Bv * Tv) / 128), 256, 0, stream>>>(
      ZBUF, WOT, bo, nullptr, Bv * Tv, Vv, Hv, PART, TLOG, tgt_nums);
  // ---- loss ----
  loss_row<<<(Bv * Tv) / 256, 256, 0, stream>>>(PART, TLOG, tgt_nums, RLOSS);
  loss_final<<<1, 256, 0, stream>>>(RLOSS, (float*)d_out);
}